// Round 3
// baseline (216.691 us; speedup 1.0000x reference)
//
#include <hip/hip_runtime.h>

// Problem constants: DIM=16, K=8 -> N=256, BATCH=256.
// U = kron(I2 (x) Ufx, I2 (x) Ufy): index i=(ah,al,bh,bl) couples only within
// fixed (ah,bh) (rows) / (ch,dh) (cols). Per batch, each 64x128 tile
// (ah,bh,ch fixed, dh merged) transforms independently via four 8x8 complex
// contractions. Output: harness compares float32 = Re(new_rho) (out_size ==
// B*N*N); a complex-interleaved path is kept for out_size >= 2*B*N*N.

// Module-owned storage for the four 8x8 complex matrices (2 KB).
// [0,64) Ufx, [64,128) Ufy, [128,192) conj Ufx, [192,256) conj Ufy.
// Rewritten by build_u_kernel on EVERY kernel_launch.
__device__ float2 g_umat[256];

__device__ __forceinline__ int swz(int idx) {
    // XOR bits {7,5,6,8} of idx into bank bits {0,1,2,4}: <=2-way (free)
    // conflicts on all four contraction axes + staging + fused store.
    int m = ((idx >> 7) & 1) | (((idx >> 5) & 1) << 1) |
            (((idx >> 6) & 1) << 2) | (((idx >> 8) & 1) << 4);
    return idx ^ m;
}

__global__ void build_u_kernel(const float* __restrict__ phi_x,
                               const float* __restrict__ phi_y) {
    const int tid = threadIdx.x;
    if (tid >= 16) return;
    const float* phi = (tid < 8) ? phi_x : phi_y;
    const int c = tid & 7;
    float ur[8], ui[8];
#pragma unroll
    for (int r = 0; r < 8; ++r) { ur[r] = (r == c) ? 1.0f : 0.0f; ui[r] = 0.0f; }
    int p = 0;
#pragma unroll
    for (int layer = 0; layer < 8; ++layer) {
#pragma unroll
        for (int j = (layer & 1); j + 1 < 8; j += 2) {
            float sa, ca, sb, cb;
            sincosf(phi[p], &sa, &ca);
            sincosf(phi[p + 1], &sb, &cb);
            p += 2;
            // M = BS @ PS(phi_b) @ BS @ PS(phi_a)
            //   = 1/2 [[ea(eb-1), i(eb+1)], [i*ea*(eb+1), (1-eb)]]
            const float ear = ca, eai = sa, ebr = cb, ebi = sb;
            const float t1r = ebr - 1.0f, t1i = ebi;
            const float t2r = ebr + 1.0f, t2i = ebi;
            const float m00r = 0.5f * (ear * t1r - eai * t1i);
            const float m00i = 0.5f * (ear * t1i + eai * t1r);
            const float m01r = -0.5f * t2i;
            const float m01i = 0.5f * t2r;
            const float e2r = ear * t2r - eai * t2i;
            const float e2i = ear * t2i + eai * t2r;
            const float m10r = -0.5f * e2i;
            const float m10i = 0.5f * e2r;
            const float m11r = 0.5f * (1.0f - ebr);
            const float m11i = -0.5f * ebi;
            const float u0r = ur[j], u0i = ui[j], u1r = ur[j + 1], u1i = ui[j + 1];
            ur[j]     = m00r * u0r - m00i * u0i + m01r * u1r - m01i * u1i;
            ui[j]     = m00r * u0i + m00i * u0r + m01r * u1i + m01i * u1r;
            ur[j + 1] = m10r * u0r - m10i * u0i + m11r * u1r - m11i * u1i;
            ui[j + 1] = m10r * u0i + m10i * u0r + m11r * u1i + m11i * u1r;
        }
    }
    float2* Um = g_umat + ((tid < 8) ? 0 : 64);
    float2* Uc = g_umat + ((tid < 8) ? 128 : 192);
#pragma unroll
    for (int r = 0; r < 8; ++r) {
        Um[r * 8 + c] = make_float2(ur[r], ui[r]);
        Uc[r * 8 + c] = make_float2(ur[r], -ui[r]);
    }
}

// In-place 8x8 complex contraction along a stride-STRIDE axis, 2 fibers/thread.
// Each thread reads its whole fiber into registers before writing it back, so
// there is no cross-thread hazard inside a pass.
template<int STRIDE>
__device__ __forceinline__ void xform(float* __restrict__ sre, float* __restrict__ sim,
                                      const float2* __restrict__ M,
                                      int base0, int base1) {
    float xr0[8], xi0[8], xr1[8], xi1[8];
#pragma unroll
    for (int k = 0; k < 8; ++k) {
        const int a0 = swz(base0 + k * STRIDE);
        const int a1 = swz(base1 + k * STRIDE);
        xr0[k] = sre[a0]; xi0[k] = sim[a0];
        xr1[k] = sre[a1]; xi1[k] = sim[a1];
    }
#pragma unroll
    for (int o = 0; o < 8; ++o) {
        float ar0 = 0.0f, ai0 = 0.0f, ar1 = 0.0f, ai1 = 0.0f;
#pragma unroll
        for (int k = 0; k < 8; ++k) {
            const float2 m = M[o * 8 + k];     // wave-uniform -> scalar loads
            ar0 = fmaf(m.x, xr0[k], ar0); ar0 = fmaf(-m.y, xi0[k], ar0);
            ai0 = fmaf(m.x, xi0[k], ai0); ai0 = fmaf(m.y, xr0[k], ai0);
            ar1 = fmaf(m.x, xr1[k], ar1); ar1 = fmaf(-m.y, xi1[k], ar1);
            ai1 = fmaf(m.x, xi1[k], ai1); ai1 = fmaf(m.y, xr1[k], ai1);
        }
        const int a0 = swz(base0 + o * STRIDE);
        const int a1 = swz(base1 + o * STRIDE);
        sre[a0] = ar0; sim[a0] = ai0;
        sre[a1] = ar1; sim[a1] = ai1;
    }
}

template<bool CPLX>
__global__ __launch_bounds__(512, 4) void qconv_main(
    const float* __restrict__ rr, const float* __restrict__ ri,
    float* __restrict__ outF) {
    __shared__ float sre[8192];
    __shared__ float sim[8192];
    const int t = threadIdx.x;
    const int bid = blockIdx.x;
    const int bh = bid & 1;
    const int ch = (bid >> 1) & 1;
    const int ah = (bid >> 2) & 1;
    const int bat = bid >> 3;
    const int row0 = ah * 128 + bh * 8;   // global row = row0 + al*16 + bl
    const int col0 = ch * 128;            // global col = col0 + c, c in [0,128)
    const size_t mb = (size_t)bat * 65536;

    // ---- Stage tile: rows are 8-contiguous runs, 128 contiguous cols -> float4
#pragma unroll
    for (int kk = 0; kk < 4; ++kk) {
        const int q = t + kk * 512;           // float4 id in [0,2048)
        const int r = q >> 5;                 // tile row (al*8+bl)
        const int c4 = q & 31;                // float4 col
        const int gi = row0 + ((r >> 3) << 4) + (r & 7);
        const size_t go = mb + (size_t)gi * 256 + (size_t)(col0 + c4 * 4);
        const float4 vr = *(const float4*)(rr + go);
        const float4 vi = *(const float4*)(ri + go);
        const int idx = r * 128 + c4 * 4;
        sre[swz(idx + 0)] = vr.x; sim[swz(idx + 0)] = vi.x;
        sre[swz(idx + 1)] = vr.y; sim[swz(idx + 1)] = vi.y;
        sre[swz(idx + 2)] = vr.z; sim[swz(idx + 2)] = vi.z;
        sre[swz(idx + 3)] = vr.w; sim[swz(idx + 3)] = vi.w;
    }
    __syncthreads();

    // tile idx = (al*8+bl)*128 + cl*16 + dh*8 + dl
    // P1: contract al with Ufx (stride 1024)
    xform<1024>(sre, sim, g_umat + 0, t, t + 512);
    __syncthreads();
    // P2: contract bl with Ufy (stride 128)
    {
        const int f0 = t, f1 = t + 512;
        const int b0 = ((f0 >> 7) << 10) | (f0 & 127);
        const int b1 = ((f1 >> 7) << 10) | (f1 & 127);
        xform<128>(sre, sim, g_umat + 64, b0, b1);
    }
    __syncthreads();
    // P3: contract cl with conj(Ufx) (stride 16)
    {
        const int f0 = t, f1 = t + 512;
        const int b0 = ((f0 >> 4) << 7) | (f0 & 15);
        const int b1 = ((f1 >> 4) << 7) | (f1 & 15);
        xform<16>(sre, sim, g_umat + 128, b0, b1);
    }
    __syncthreads();

    // P4: contract dl with conj(Ufy) (stride 1), FUSED with the global store.
    // Fiber f: base = rows(f>>4) | cl((f>>1)&7) | dh(f&1); its 8 outputs are 8
    // consecutive global columns -> two float4 stores (real) per fiber.
    {
        const float2* __restrict__ M = g_umat + 192;
#pragma unroll
        for (int h = 0; h < 2; ++h) {
            const int f = t + h * 512;
            const int base = ((f >> 4) << 7) | (((f >> 1) & 7) << 4) | ((f & 1) << 3);
            float xr[8], xi[8];
#pragma unroll
            for (int k = 0; k < 8; ++k) {
                const int a = swz(base + k);
                xr[k] = sre[a]; xi[k] = sim[a];
            }
            const int r = f >> 4;
            const int gi = row0 + ((r >> 3) << 4) + (r & 7);
            const int c = base & 127;
            if (!CPLX) {
                float o0[8];
#pragma unroll
                for (int o = 0; o < 8; ++o) {
                    float ar = 0.0f;
#pragma unroll
                    for (int k = 0; k < 8; ++k) {
                        const float2 m = M[o * 8 + k];
                        ar = fmaf(m.x, xr[k], ar);
                        ar = fmaf(-m.y, xi[k], ar);
                    }
                    o0[o] = ar;
                }
                float* dst = outF + mb + (size_t)gi * 256 + (size_t)(col0 + c);
                *(float4*)(dst + 0) = make_float4(o0[0], o0[1], o0[2], o0[3]);
                *(float4*)(dst + 4) = make_float4(o0[4], o0[5], o0[6], o0[7]);
            } else {
                float2* dst = (float2*)outF + mb + (size_t)gi * 256 + (size_t)(col0 + c);
#pragma unroll
                for (int o = 0; o < 8; ++o) {
                    float ar = 0.0f, ai = 0.0f;
#pragma unroll
                    for (int k = 0; k < 8; ++k) {
                        const float2 m = M[o * 8 + k];
                        ar = fmaf(m.x, xr[k], ar); ar = fmaf(-m.y, xi[k], ar);
                        ai = fmaf(m.x, xi[k], ai); ai = fmaf(m.y, xr[k], ai);
                    }
                    dst[o] = make_float2(ar, ai);
                }
            }
        }
    }
}

extern "C" void kernel_launch(void* const* d_in, const int* in_sizes, int n_in,
                              void* d_out, int out_size, void* d_ws, size_t ws_size,
                              hipStream_t stream) {
    const float* rr = (const float*)d_in[0];
    const float* ri = (const float*)d_in[1];
    const float* px = (const float*)d_in[2];
    const float* py = (const float*)d_in[3];
    const int batch = in_sizes[0] / 65536;
    const long long total = (long long)batch * 65536;
    build_u_kernel<<<1, 64, 0, stream>>>(px, py);
    if ((long long)out_size >= 2 * total) {
        // complex64 interleaved output
        qconv_main<true><<<batch * 8, 512, 0, stream>>>(rr, ri, (float*)d_out);
    } else {
        // float32 output = Re(new_rho)
        qconv_main<false><<<batch * 8, 512, 0, stream>>>(rr, ri, (float*)d_out);
    }
}

// Round 4
// 212.865 us; speedup vs baseline: 1.0180x; 1.0180x over previous
//
#include <hip/hip_runtime.h>

// DIM=16, K=8 -> N=256, BATCH=256. U = kron(I2 (x) Ufx, I2 (x) Ufy).
// Row index (ah,al,bh,bl), col index (ch,cl,dh,dl). ah,bh,ch,dh are inert ->
// block = (batch, ah,bh,ch,dh): a 64x64 complex tile (rows (al,bl), cols
// (cl,dl)) transformed by four 8x8 complex contractions:
//   P1: al <- Ufx,  P2: bl <- Ufy,  P3: cl <- conj Ufx,  P4: dl <- conj Ufy.
// LDS layout (complex idx): L(al,bl,cl,dl) = al*512 + bl*64 + (cl^bl)*8 + (dl^cl)
// -> bank-optimal for every pass; tap addresses are base ^ {512k,72k,9k,k}.

__device__ float2 g_umat[256];  // [0,64) Ufx | [64,128) Ufy | [128,192) conj Ufx | [192,256) conj Ufy

__global__ void build_u_kernel(const float* __restrict__ phi_x,
                               const float* __restrict__ phi_y) {
    const int tid = threadIdx.x;
    if (tid >= 16) return;
    const float* phi = (tid < 8) ? phi_x : phi_y;
    const int c = tid & 7;
    float ur[8], ui[8];
#pragma unroll
    for (int r = 0; r < 8; ++r) { ur[r] = (r == c) ? 1.0f : 0.0f; ui[r] = 0.0f; }
    int p = 0;
#pragma unroll
    for (int layer = 0; layer < 8; ++layer) {
#pragma unroll
        for (int j = (layer & 1); j + 1 < 8; j += 2) {
            float sa, ca, sb, cb;
            sincosf(phi[p], &sa, &ca);
            sincosf(phi[p + 1], &sb, &cb);
            p += 2;
            // M = BS @ PS(phi_b) @ BS @ PS(phi_a)
            //   = 1/2 [[ea(eb-1), i(eb+1)], [i*ea*(eb+1), (1-eb)]]
            const float ear = ca, eai = sa, ebr = cb, ebi = sb;
            const float t1r = ebr - 1.0f, t1i = ebi;
            const float t2r = ebr + 1.0f, t2i = ebi;
            const float m00r = 0.5f * (ear * t1r - eai * t1i);
            const float m00i = 0.5f * (ear * t1i + eai * t1r);
            const float m01r = -0.5f * t2i;
            const float m01i = 0.5f * t2r;
            const float e2r = ear * t2r - eai * t2i;
            const float e2i = ear * t2i + eai * t2r;
            const float m10r = -0.5f * e2i;
            const float m10i = 0.5f * e2r;
            const float m11r = 0.5f * (1.0f - ebr);
            const float m11i = -0.5f * ebi;
            const float u0r = ur[j], u0i = ui[j], u1r = ur[j + 1], u1i = ui[j + 1];
            ur[j]     = m00r * u0r - m00i * u0i + m01r * u1r - m01i * u1i;
            ui[j]     = m00r * u0i + m00i * u0r + m01r * u1i + m01i * u1r;
            ur[j + 1] = m10r * u0r - m10i * u0i + m11r * u1r - m11i * u1i;
            ui[j + 1] = m10r * u0i + m10i * u0r + m11r * u1i + m11i * u1r;
        }
    }
    float2* Um = g_umat + ((tid < 8) ? 0 : 64);
    float2* Uc = g_umat + ((tid < 8) ? 128 : 192);
#pragma unroll
    for (int r = 0; r < 8; ++r) {
        Um[r * 8 + c] = make_float2(ur[r], ui[r]);
        Uc[r * 8 + c] = make_float2(ur[r], -ui[r]);
    }
}

// In-place 8-tap complex contraction on one fiber (indices precomputed,
// compile-time-indexed). Reads all taps into registers before writing.
__device__ __forceinline__ void xpass(float2* __restrict__ sm,
                                      const float2* __restrict__ M,
                                      const int* idx) {
    float xr[8], xi[8];
#pragma unroll
    for (int k = 0; k < 8; ++k) {
        const float2 v = sm[idx[k]];
        xr[k] = v.x; xi[k] = v.y;
    }
#pragma unroll
    for (int o = 0; o < 8; ++o) {
        float ar = 0.0f, ai = 0.0f;
#pragma unroll
        for (int k = 0; k < 8; ++k) {
            const float2 m = M[o * 8 + k];   // wave-uniform -> scalar loads
            ar = fmaf(m.x, xr[k], ar); ar = fmaf(-m.y, xi[k], ar);
            ai = fmaf(m.x, xi[k], ai); ai = fmaf(m.y, xr[k], ai);
        }
        sm[idx[o]] = make_float2(ar, ai);
    }
}

template<bool CPLX>
__global__ __launch_bounds__(512, 8) void qconv_main(
    const float* __restrict__ rr, const float* __restrict__ ri,
    float* __restrict__ outF) {
    __shared__ float2 sm[4096];              // 32 KB -> 4 blocks/CU
    const int t = threadIdx.x;
    const int bid = blockIdx.x;
    const int dh = bid & 1;
    const int ch = (bid >> 1) & 1;
    const int bh = (bid >> 2) & 1;
    const int ah = (bid >> 3) & 1;
    const int bat = bid >> 4;
    const int row0 = ah * 128 + bh * 8;      // global row = row0 + al*16 + bl
    const int col0 = ch * 128 + dh * 8;      // global col = col0 + cl*16 + dl
    const size_t mb = (size_t)bat * 65536;

    // ---- stage: thread (al,bl,cl) loads its 8-float dl-run of rr/ri
    {
        const int al = t >> 6, bl = (t >> 3) & 7, cl = t & 7;
        const int gi = row0 + al * 16 + bl;
        const size_t go = mb + (size_t)gi * 256 + (size_t)(col0 + cl * 16);
        const float4 r0 = *(const float4*)(rr + go);
        const float4 r1 = *(const float4*)(rr + go + 4);
        const float4 i0 = *(const float4*)(ri + go);
        const float4 i1 = *(const float4*)(ri + go + 4);
        const int base = al * 512 + bl * 64 + ((cl ^ bl) << 3) + cl;  // dl=0 slot
        sm[base ^ 0] = make_float2(r0.x, i0.x);
        sm[base ^ 1] = make_float2(r0.y, i0.y);
        sm[base ^ 2] = make_float2(r0.z, i0.z);
        sm[base ^ 3] = make_float2(r0.w, i0.w);
        sm[base ^ 4] = make_float2(r1.x, i1.x);
        sm[base ^ 5] = make_float2(r1.y, i1.y);
        sm[base ^ 6] = make_float2(r1.z, i1.z);
        sm[base ^ 7] = make_float2(r1.w, i1.w);
    }
    __syncthreads();

    // P1: contract al with Ufx. Taps at base + k*512 (imm offsets).
    {
        const int bl = t >> 6, cl = (t >> 3) & 7, dl = t & 7;
        const int base = bl * 64 + ((cl ^ bl) << 3) + (dl ^ cl);
        int idx[8];
#pragma unroll
        for (int k = 0; k < 8; ++k) idx[k] = base + (k << 9);
        xpass(sm, g_umat + 0, idx);
    }
    __syncthreads();

    // P2: contract bl with Ufy. Taps at base ^ 72k.
    {
        const int al = t >> 6, cl = (t >> 3) & 7, dl = t & 7;
        const int base = al * 512 + (cl << 3) + (dl ^ cl);
        int idx[8];
#pragma unroll
        for (int k = 0; k < 8; ++k) idx[k] = base ^ (72 * k);
        xpass(sm, g_umat + 64, idx);
    }
    __syncthreads();

    // P3: contract cl with conj Ufx. Taps at base ^ 9k.
    {
        const int al = t >> 6, bl = (t >> 3) & 7, dl = t & 7;
        const int base = al * 512 + bl * 64 + (bl << 3) + dl;
        int idx[8];
#pragma unroll
        for (int k = 0; k < 8; ++k) idx[k] = base ^ (9 * k);
        xpass(sm, g_umat + 128, idx);
    }
    __syncthreads();

    // P4: contract dl with conj Ufy, fused with the global store.
    {
        const int al = t >> 6, bl = (t >> 3) & 7, cl = t & 7;
        const int base = al * 512 + bl * 64 + ((cl ^ bl) << 3) + cl;
        float xr[8], xi[8];
#pragma unroll
        for (int k = 0; k < 8; ++k) {
            const float2 v = sm[base ^ k];
            xr[k] = v.x; xi[k] = v.y;
        }
        const int gi = row0 + al * 16 + bl;
        const size_t go = mb + (size_t)gi * 256 + (size_t)(col0 + cl * 16);
        const float2* __restrict__ M = g_umat + 192;
        if (!CPLX) {
            float o0[8];
#pragma unroll
            for (int o = 0; o < 8; ++o) {
                float ar = 0.0f;
#pragma unroll
                for (int k = 0; k < 8; ++k) {
                    const float2 m = M[o * 8 + k];
                    ar = fmaf(m.x, xr[k], ar);
                    ar = fmaf(-m.y, xi[k], ar);
                }
                o0[o] = ar;
            }
            *(float4*)(outF + go)     = make_float4(o0[0], o0[1], o0[2], o0[3]);
            *(float4*)(outF + go + 4) = make_float4(o0[4], o0[5], o0[6], o0[7]);
        } else {
            float2* dst = (float2*)outF + go;
#pragma unroll
            for (int o = 0; o < 8; ++o) {
                float ar = 0.0f, ai = 0.0f;
#pragma unroll
                for (int k = 0; k < 8; ++k) {
                    const float2 m = M[o * 8 + k];
                    ar = fmaf(m.x, xr[k], ar); ar = fmaf(-m.y, xi[k], ar);
                    ai = fmaf(m.x, xi[k], ai); ai = fmaf(m.y, xr[k], ai);
                }
                dst[o] = make_float2(ar, ai);
            }
        }
    }
}

extern "C" void kernel_launch(void* const* d_in, const int* in_sizes, int n_in,
                              void* d_out, int out_size, void* d_ws, size_t ws_size,
                              hipStream_t stream) {
    const float* rr = (const float*)d_in[0];
    const float* ri = (const float*)d_in[1];
    const float* px = (const float*)d_in[2];
    const float* py = (const float*)d_in[3];
    const int batch = in_sizes[0] / 65536;
    const long long total = (long long)batch * 65536;
    build_u_kernel<<<1, 64, 0, stream>>>(px, py);
    if ((long long)out_size >= 2 * total) {
        qconv_main<true><<<batch * 16, 512, 0, stream>>>(rr, ri, (float*)d_out);
    } else {
        qconv_main<false><<<batch * 16, 512, 0, stream>>>(rr, ri, (float*)d_out);
    }
}